// Round 14
// baseline (88.156 us; speedup 1.0000x reference)
//
#include <hip/hip_runtime.h>

using f16x8 = _Float16 __attribute__((ext_vector_type(8)));
using f32x4 = float __attribute__((ext_vector_type(4)));

#define BS      8192
#define IN_DIM  4096
#define NB      64
#define BD      64
#define HID     256
#define OD      64
#define GYP     4          // 4 row-groups x 2048 rows = 8192
#define SLABS   16         // 16 slabs x 128 rows per WG
#define SROWS   128

__device__ __forceinline__ float gelu_f(float z) {
    // x*sigmoid(1.702x): exp(-1.702 z) = exp2(-2.4554443 z)
    float e = __builtin_amdgcn_exp2f(z * -2.4554443f);
    float r = __builtin_amdgcn_rcpf(e + 1.0f);
    return z * r;
}

// ---- prep: build fragment-major f16 weight images in d_ws (once per launch).
__global__ __launch_bounds__(256) void prep_weights(
    const float* __restrict__ w1g, const float* __restrict__ w2g,
    f16x8* __restrict__ ws1, f16x8* __restrict__ ws2) {
    const int n = blockIdx.x;
    const int t = threadIdx.x;
    const float* W1n = w1g + (size_t)n * (BD * HID);
    const float* W2n = w2g + (size_t)n * (HID * OD);
    #pragma unroll
    for (int it = 0; it < 8; ++it) {
        int e = it * 256 + t;
        {
            int ht = e >> 7, ks = (e >> 6) & 1, le = e & 63;
            int ge = le >> 4, oo = le & 15;
            f16x8 v;
            #pragma unroll
            for (int j = 0; j < 8; ++j)
                v[j] = (_Float16)W1n[(size_t)(ks * 32 + ge * 8 + j) * HID + ht * 16 + oo];
            ws1[(size_t)n * 2048 + e] = v;
        }
        {
            int p = e >> 8, n2 = (e >> 6) & 3, le = e & 63;
            int ge = le >> 4, ce = le & 15;
            f16x8 v;
            #pragma unroll
            for (int j = 0; j < 8; ++j)
                v[j] = (_Float16)W2n[(size_t)(p * 32 + ((j >> 2) << 4) + ge * 4 + (j & 3)) * OD + n2 * 16 + ce];
            ws2[(size_t)n * 2048 + e] = v;
        }
    }
}

// Persistent 1-WG/CU kernel with async global->LDS double-buffered x staging.
// Per slab: issue DMA of slab s+1 (global_load_lds, no VGPR cost), compute
// slab s from LDS, store, barrier (compiler's pre-barrier vmcnt(0) drains the
// DMA *after* compute -> latency hidden). x LDS uses a source-side XOR chunk
// swizzle (legal: global addr of global_load_lds is per-lane) so the
// ds_read_b128 fragment reads hit the conflict-free minimum.
__global__ __launch_bounds__(512, 4) void blockmlp_kernel(
    const float* __restrict__ xg,
    const f16x8* __restrict__ ws1, const f16x8* __restrict__ ws2,
    const float* __restrict__ b1g, const float* __restrict__ b2g,
    float* __restrict__ outg) {

    __shared__ f16x8 W1F[2048];            // 32 KB  [ht=16][ks=2][lane]
    __shared__ f16x8 W2L[2048];            // 32 KB  [p=8][n2=4][lane]
    __shared__ float b1L[HID];             // 1 KB
    __shared__ float xbuf[2][SROWS * 64];  // 2 x 32 KB x double-buffer

    const int tid = threadIdx.x;
    const int w   = tid >> 6;
    const int l   = tid & 63;
    const int g   = l >> 4;
    const int l15 = l & 15;
    const int n   = blockIdx.x;           // R8 mapping: XCD = n%8 (L2-resident weights)

    // ---- stage prebuilt weight fragments (coalesced b128 loads + b128 LDS writes)
    const f16x8* p1 = ws1 + (size_t)n * 2048;
    const f16x8* p2 = ws2 + (size_t)n * 2048;
    f16x8 s1[4], s2[4];
    #pragma unroll
    for (int it = 0; it < 4; ++it) { s1[it] = p1[it * 512 + tid]; }
    #pragma unroll
    for (int it = 0; it < 4; ++it) { s2[it] = p2[it * 512 + tid]; }
    #pragma unroll
    for (int it = 0; it < 4; ++it) { W1F[it * 512 + tid] = s1[it]; }
    #pragma unroll
    for (int it = 0; it < 4; ++it) { W2L[it * 512 + tid] = s2[it]; }

    if (tid < HID) b1L[tid] = b1g[n * HID + tid];

    float b2b[4];
    #pragma unroll
    for (int n2 = 0; n2 < 4; ++n2) b2b[n2] = b2g[n * OD + n2 * 16 + l15];

    const int wgrow = blockIdx.y * (SLABS * SROWS);

    // ---- async-stage slab 0 into xbuf[0] (entry e=(r,c): content = chunk c^(r&7))
    #pragma unroll
    for (int i = 0; i < 4; ++i) {
        int e = i * 512 + tid;
        int r = e >> 4, c = e & 15;
        int cs = c ^ (r & 7);
        const float* src = xg + (size_t)(wgrow + r) * IN_DIM + n * BD + cs * 4;
        __builtin_amdgcn_global_load_lds(
            (const __attribute__((address_space(1))) void*)src,
            (__attribute__((address_space(3))) void*)&xbuf[0][(i * 512 + (tid & 448)) * 4],
            16, 0, 0);
    }

    __syncthreads();   // weights + slab0 ready (compiler drains vmcnt before barrier)

    for (int s = 0; s < SLABS; ++s) {
        const int cur = s & 1;
        const int row0 = wgrow + s * SROWS;

        // ---- issue DMA for slab s+1 into the other buffer (overlaps compute below)
        if (s + 1 < SLABS) {
            #pragma unroll
            for (int i = 0; i < 4; ++i) {
                int e = i * 512 + tid;
                int r = e >> 4, c = e & 15;
                int cs = c ^ (r & 7);
                const float* src = xg + (size_t)(row0 + SROWS + r) * IN_DIM + n * BD + cs * 4;
                __builtin_amdgcn_global_load_lds(
                    (const __attribute__((address_space(1))) void*)src,
                    (__attribute__((address_space(3))) void*)&xbuf[cur ^ 1][(i * 512 + (tid & 448)) * 4],
                    16, 0, 0);
            }
        }

        // ---- x fragments from LDS: wave w owns rows row0 + w*16 + 0..15
        // lane (g,l15) reads row r=w*16+l15, logical chunks ks*8+g*2+{0,1}
        f16x8 xa[2];
        {
            const int r = w * 16 + l15;
            const float* xb = &xbuf[cur][r * 64];
            #pragma unroll
            for (int ks = 0; ks < 2; ++ks) {
                int pc0 = (ks * 8 + g * 2 + 0) ^ (l15 & 7);
                int pc1 = (ks * 8 + g * 2 + 1) ^ (l15 & 7);
                f32x4 c0 = *(const f32x4*)&xb[pc0 * 4];
                f32x4 c1v = *(const f32x4*)&xb[pc1 * 4];
                f16x8 v;
                v[0] = (_Float16)c0[0]; v[1] = (_Float16)c0[1];
                v[2] = (_Float16)c0[2]; v[3] = (_Float16)c0[3];
                v[4] = (_Float16)c1v[0]; v[5] = (_Float16)c1v[1];
                v[6] = (_Float16)c1v[2]; v[7] = (_Float16)c1v[3];
                xa[ks] = v;
            }
        }

        // ---- compute 16-row tile (R8-proven math; rs-dim replaced by w-tiling)
        f32x4 c2[4];
        #pragma unroll
        for (int n2 = 0; n2 < 4; ++n2) {
            f32x4 ci;
            ci[0] = b2b[n2]; ci[1] = b2b[n2]; ci[2] = b2b[n2]; ci[3] = b2b[n2];
            c2[n2] = ci;
        }

        #pragma unroll
        for (int p = 0; p < 8; ++p) {
            f32x4 c1[2];
            #pragma unroll
            for (int htl = 0; htl < 2; ++htl) {
                f32x4 c = *(const f32x4*)&b1L[(p * 2 + htl) * 16 + g * 4];
                #pragma unroll
                for (int ks = 0; ks < 2; ++ks) {
                    f16x8 wf = W1F[(((p * 2 + htl) * 2) + ks) * 64 + l];
                    c = __builtin_amdgcn_mfma_f32_16x16x32_f16(wf, xa[ks], c, 0, 0, 0);
                }
                c1[htl] = c;
            }
            f16x8 a2;
            #pragma unroll
            for (int q = 0; q < 4; ++q) {
                a2[q]     = (_Float16)gelu_f(c1[0][q]);
                a2[q + 4] = (_Float16)gelu_f(c1[1][q]);
            }
            #pragma unroll
            for (int n2 = 0; n2 < 4; ++n2) {
                f16x8 bf = W2L[(p * 4 + n2) * 64 + l];
                c2[n2] = __builtin_amdgcn_mfma_f32_16x16x32_f16(a2, bf, c2[n2], 0, 0, 0);
            }
        }

        // ---- store (bias already in accumulators)
        #pragma unroll
        for (int n2 = 0; n2 < 4; ++n2)
            #pragma unroll
            for (int q = 0; q < 4; ++q) {
                int row = row0 + w * 16 + g * 4 + q;
                outg[(size_t)row * IN_DIM + n * BD + n2 * 16 + l15] = c2[n2][q];
            }

        // barrier: compiler-emitted vmcnt(0) drains the s+1 DMA (issued a full
        // compute-phase ago) and synchronizes buffer swap.
        __syncthreads();
    }
}

extern "C" void kernel_launch(void* const* d_in, const int* in_sizes, int n_in,
                              void* d_out, int out_size, void* d_ws, size_t ws_size,
                              hipStream_t stream) {
    const float* x  = (const float*)d_in[0];
    const float* W1 = (const float*)d_in[1];
    const float* b1 = (const float*)d_in[2];
    const float* W2 = (const float*)d_in[3];
    const float* b2 = (const float*)d_in[4];
    float* out = (float*)d_out;

    f16x8* ws1 = (f16x8*)d_ws;            // 64*2048*16 B = 2 MB
    f16x8* ws2 = ws1 + (size_t)NB * 2048; // +2 MB  (ws_size must be >= 4 MB)

    hipLaunchKernelGGL(prep_weights, dim3(NB), dim3(256), 0, stream, W1, W2, ws1, ws2);
    hipLaunchKernelGGL(blockmlp_kernel, dim3(NB, GYP), dim3(512), 0, stream,
                       x, ws1, ws2, b1, b2, out);
}